// Round 2
// baseline (230.178 us; speedup 1.0000x reference)
//
#include <hip/hip_runtime.h>

#define EPSV 1e-7f

typedef __bf16 bf16x8 __attribute__((ext_vector_type(8)));
typedef float  f32x4  __attribute__((ext_vector_type(4)));
typedef float  f32x2  __attribute__((ext_vector_type(2)));
typedef unsigned int   u32x4 __attribute__((ext_vector_type(4)));
typedef unsigned short u16x8 __attribute__((ext_vector_type(8)));
typedef unsigned short u16x4 __attribute__((ext_vector_type(4)));

__device__ __forceinline__ unsigned short f2bf(float f) {
    unsigned int u = __float_as_uint(f);
    return (unsigned short)((u + 0x7FFFu + ((u >> 16) & 1u)) >> 16);
}
__device__ __forceinline__ float bf2f(unsigned short u) {
    return __uint_as_float(((unsigned int)u) << 16);
}
__device__ __forceinline__ void split2(float f, unsigned short& hi, unsigned short& lo) {
    hi = f2bf(f);
    lo = f2bf(f - bf2f(hi));
}
__device__ __forceinline__ float sigf(float x) {
    return 1.0f / (1.0f + __expf(-x));
}
__device__ __forceinline__ float tanhfast(float x) {
    float cx = fminf(fmaxf(x, -15.0f), 15.0f);
    float e = __expf(2.0f * cx);
    return (e - 1.0f) / (e + 1.0f);
}

#define MFMA16(A, B, C) __builtin_amdgcn_mfma_f32_16x16x32_bf16(A, B, C, 0, 0, 0)
#define BC8(x) __builtin_bit_cast(bf16x8, x)

// Row strides (ushorts). Chosen so dword-stride % 32 == 4 -> 2-way LDS bank
// aliasing on A-frag reads (free per m136).
#define XS 200   // xh: x_hi[0..63] h_hi[64..95] x_lo[96..159] h_lo[160..191]
#define MS 136   // mlps/hids: cat_hi[0..63] cat_lo[64..127]
#define ZS 20    // zT: [unit][brow] fp32

// Block = 256 threads (4 waves), owns 16 batch rows for the full sequence.
// All GEMMs use bf16 hi/lo split (3-term) -> effectively fp32 precision.
__global__ __launch_bounds__(256) void tutina_kernel(
    const float* __restrict__ history, const float* __restrict__ control,
    const float* __restrict__ forecasts,
    const float* __restrict__ h_mean, const float* __restrict__ h_var,
    const float* __restrict__ c_mean, const float* __restrict__ c_var,
    const float* __restrict__ f_mean, const float* __restrict__ f_var,
    const float* __restrict__ conv_w, const float* __restrict__ conv_b,
    const float* __restrict__ lstm_k, const float* __restrict__ lstm_rk,
    const float* __restrict__ lstm_b,
    const float* __restrict__ w1, const float* __restrict__ b1,
    const float* __restrict__ w2, const float* __restrict__ b2,
    float* __restrict__ out)
{
    __shared__ unsigned short xh[16 * XS];
    __shared__ float zT[128 * ZS];
    __shared__ unsigned short mlps[16 * MS];
    __shared__ unsigned short hids[16 * MS];
    __shared__ float fcs[48 * 64];   // fc conv precompute [t][b*4+u] fp32

    const int tid  = threadIdx.x;
    const int lane = tid & 63;
    const int wid  = tid >> 6;
    const int l15  = lane & 15;
    const int l4   = lane >> 4;
    const int b0   = blockIdx.x * 16;

    // ---- prologue: zero staging buffers (h=0 init, pad regions) ----
    for (int i = tid; i < 16 * XS; i += 256) xh[i] = 0;
    for (int i = tid; i < 16 * MS; i += 256) mlps[i] = 0;
    __syncthreads();

    // ---- weight fragments, hi+lo, held in VGPRs for whole kernel ----
    const int uz = wid * 32;          // wave's z-unit base (0..96)
    const int j1 = wid * 16 + l15;    // wave's MLP/out column (0..63)

    auto bfrag2 = [&](const float* W, int ldw, int kbase, int j, int kmax,
                      bf16x8& H, bf16x8& L) {
        u16x8 h, l;
#pragma unroll
        for (int i = 0; i < 8; i++) {
            int k = kbase + l4 * 8 + i;
            float w = (k < kmax) ? W[k * ldw + j] : 0.0f;
            unsigned short hh, ll;
            split2(w, hh, ll);
            h[i] = hh; l[i] = ll;
        }
        H = BC8(h); L = BC8(l);
    };
    bf16x8 fK00h, fK00l, fK01h, fK01l, fK10h, fK10l, fK11h, fK11l;
    bf16x8 fR0h, fR0l, fR1h, fR1l;
    bf16x8 fW10h, fW10l, fW11h, fW11l, fW20h, fW20l, fW21h, fW21l;
    bfrag2(lstm_k, 128,  0, uz + l15,      64, fK00h, fK00l);
    bfrag2(lstm_k, 128,  0, uz + 16 + l15, 64, fK01h, fK01l);
    bfrag2(lstm_k, 128, 32, uz + l15,      64, fK10h, fK10l);
    bfrag2(lstm_k, 128, 32, uz + 16 + l15, 64, fK11h, fK11l);
    bfrag2(lstm_rk, 128, 0, uz + l15,      32, fR0h, fR0l);
    bfrag2(lstm_rk, 128, 0, uz + 16 + l15, 32, fR1h, fR1l);
    bfrag2(w1, 64,  0, j1, 52, fW10h, fW10l);
    bfrag2(w1, 64, 32, j1, 52, fW11h, fW11l);
    bfrag2(w2, 64,  0, j1, 64, fW20h, fW20l);
    bfrag2(w2, 64, 32, j1, 64, fW21h, fW21l);

    // per-lane constants
    float b1j = b1[j1], b2j = b2[j1];
    float hmj = h_mean[j1];
    float hsj = 1.0f / fmaxf(sqrtf(h_var[j1]), EPSV);

    // gate cells: thread handles (u=ug, rows bg, bg+1)
    const int ug = tid >> 3;
    const int bg = (tid & 7) * 2;
    float bzi = lstm_b[ug], bzf = lstm_b[32 + ug];
    float bzg = lstm_b[64 + ug], bzo = lstm_b[96 + ug];
    float cg0 = 0.0f, cg1 = 0.0f;

    // x-staging mapping: row rs, float4-group cs
    const int rs = tid >> 4;
    const int cs = tid & 15;
    float hm4[4], hs4[4];
#pragma unroll
    for (int q = 0; q < 4; q++) {
        hm4[q] = h_mean[cs * 4 + q];
        hs4[q] = 1.0f / fmaxf(sqrtf(h_var[cs * 4 + q]), EPSV);
    }
    const float* hrow = history + (size_t)(b0 + rs) * (168 * 64) + cs * 4;

    // cn staging mapping (threads 0..63)
    const int rc = tid >> 2, cc = (tid & 3) * 4;
    float cm4[4], cs4[4];
#pragma unroll
    for (int q = 0; q < 4; q++) {
        cm4[q] = c_mean[cc + q];
        cs4[q] = 1.0f / fmaxf(sqrtf(c_var[cc + q]), EPSV);
    }

    // ---- fc conv precompute: fc[t][b][u] fp32 ----
    {
        float fm  = f_mean[0];
        float fsc = 1.0f / fmaxf(sqrtf(f_var[0]), EPSV);
        for (int cell = tid; cell < 48 * 64; cell += 256) {
            int t = cell >> 6;
            int b = (cell >> 2) & 15;
            int u = cell & 3;
            const float* fp = forecasts + ((size_t)(b0 + b) * 49 + t) * 8;
            float acc = conv_b[u];
#pragma unroll
            for (int k = 0; k < 8; k++) {
                acc += (fp[k]     - fm) * fsc * conv_w[k * 4 + u];
                acc += (fp[8 + k] - fm) * fsc * conv_w[32 + k * 4 + u];
            }
            fcs[cell] = acc;
        }
    }

    auto stage_x = [&](const f32x4& v) {
        u16x4 oh, ol;
#pragma unroll
        for (int q = 0; q < 4; q++) {
            float n = (v[q] - hm4[q]) * hs4[q];
            unsigned short hh, ll;
            split2(n, hh, ll);
            oh[q] = hh; ol[q] = ll;
        }
        *(u16x4*)&xh[rs * XS + cs * 4]      = oh;
        *(u16x4*)&xh[rs * XS + 96 + cs * 4] = ol;
    };

    // ---- stage x_0 ----
    stage_x(*(const f32x4*)(hrow));
    __syncthreads();

    // ---- LSTM z GEMM: [x(64)|h(32)] (16x96) @ [K;R] (96x128), hi/lo split ----
    auto lstm_mfma_phase = [&]() {
        const int base = l15 * XS + l4 * 8;
        bf16x8 a0  = BC8(*(const u32x4*)&xh[base]);
        bf16x8 a1  = BC8(*(const u32x4*)&xh[base + 32]);
        bf16x8 a2  = BC8(*(const u32x4*)&xh[base + 64]);
        bf16x8 a0l = BC8(*(const u32x4*)&xh[base + 96]);
        bf16x8 a1l = BC8(*(const u32x4*)&xh[base + 128]);
        bf16x8 a2l = BC8(*(const u32x4*)&xh[base + 160]);
        f32x4 z0 = {0.f, 0.f, 0.f, 0.f}, z1 = {0.f, 0.f, 0.f, 0.f};
        z0 = MFMA16(a0,  fK00h, z0);
        z0 = MFMA16(a1,  fK10h, z0);
        z0 = MFMA16(a2,  fR0h,  z0);
        z0 = MFMA16(a0l, fK00h, z0);
        z0 = MFMA16(a1l, fK10h, z0);
        z0 = MFMA16(a2l, fR0h,  z0);
        z0 = MFMA16(a0,  fK00l, z0);
        z0 = MFMA16(a1,  fK10l, z0);
        z0 = MFMA16(a2,  fR0l,  z0);
        z1 = MFMA16(a0,  fK01h, z1);
        z1 = MFMA16(a1,  fK11h, z1);
        z1 = MFMA16(a2,  fR1h,  z1);
        z1 = MFMA16(a0l, fK01h, z1);
        z1 = MFMA16(a1l, fK11h, z1);
        z1 = MFMA16(a2l, fR1h,  z1);
        z1 = MFMA16(a0,  fK01l, z1);
        z1 = MFMA16(a1,  fK11l, z1);
        z1 = MFMA16(a2,  fR1l,  z1);
        *(f32x4*)&zT[(uz + l15)      * ZS + l4 * 4] = z0;
        *(f32x4*)&zT[(uz + 16 + l15) * ZS + l4 * 4] = z1;
    };
    auto gate_phase = [&]() {
        f32x2 Zi = *(const f32x2*)&zT[ug        * ZS + bg];
        f32x2 Zf = *(const f32x2*)&zT[(32 + ug) * ZS + bg];
        f32x2 Zg = *(const f32x2*)&zT[(64 + ug) * ZS + bg];
        f32x2 Zo = *(const f32x2*)&zT[(96 + ug) * ZS + bg];
        cg0 = sigf(Zf[0] + bzf) * cg0 + sigf(Zi[0] + bzi) * tanhfast(Zg[0] + bzg);
        cg1 = sigf(Zf[1] + bzf) * cg1 + sigf(Zi[1] + bzi) * tanhfast(Zg[1] + bzg);
        float h2a = sigf(Zo[0] + bzo) * tanhfast(cg0);
        float h2b = sigf(Zo[1] + bzo) * tanhfast(cg1);
        unsigned short hh, hl;
        split2(h2a, hh, hl);
        xh[bg * XS + 64 + ug]  = hh;
        xh[bg * XS + 160 + ug] = hl;
        mlps[bg * MS + ug]      = hh;
        mlps[bg * MS + 64 + ug] = hl;
        split2(h2b, hh, hl);
        xh[(bg + 1) * XS + 64 + ug]  = hh;
        xh[(bg + 1) * XS + 160 + ug] = hl;
        mlps[(bg + 1) * MS + ug]      = hh;
        mlps[(bg + 1) * MS + 64 + ug] = hl;
    };

    // ---- encoder: 168 steps ----
    for (int t = 0; t < 168; ++t) {
        int tn = (t < 167) ? t + 1 : 167;
        f32x4 vnx = *(const f32x4*)(hrow + (size_t)tn * 64);  // prefetch next x

        lstm_mfma_phase();
        __syncthreads();   // z ready; xh reads done

        gate_phase();      // h2 -> xh.h, mlps.h ; c stays in regs
        stage_x(vnx);      // x-region; disjoint from h-region writes
        __syncthreads();
    }

    // ---- latest = history[:, -1, :] (C/D layout: col j1, rows l4*4+r) ----
    float lat0 = history[((size_t)(b0 + l4 * 4 + 0) * 168 + 167) * 64 + j1];
    float lat1 = history[((size_t)(b0 + l4 * 4 + 1) * 168 + 167) * 64 + j1];
    float lat2 = history[((size_t)(b0 + l4 * 4 + 2) * 168 + 167) * 64 + j1];
    float lat3 = history[((size_t)(b0 + l4 * 4 + 3) * 168 + 167) * 64 + j1];

    auto stage_cnfc = [&](int t) {
        if (tid < 64) {
            f32x4 v = *(const f32x4*)(control + ((size_t)(b0 + rc) * 48 + t) * 16 + cc);
            u16x4 oh, ol;
#pragma unroll
            for (int q = 0; q < 4; q++) {
                float n = (v[q] - cm4[q]) * cs4[q];
                unsigned short hh, ll;
                split2(n, hh, ll);
                oh[q] = hh; ol[q] = ll;
            }
            *(u16x4*)&mlps[rc * MS + 32 + cc]      = oh;
            *(u16x4*)&mlps[rc * MS + 64 + 32 + cc] = ol;
        } else if (tid < 128) {
            int q = tid - 64;
            unsigned short hh, ll;
            split2(fcs[t * 64 + q], hh, ll);
            mlps[(q >> 2) * MS + 48 + (q & 3)]      = hh;
            mlps[(q >> 2) * MS + 64 + 48 + (q & 3)] = ll;
        }
    };

    auto run_mlp = [&]() {
        const int mbase = l15 * MS + l4 * 8;
        bf16x8 m0  = BC8(*(const u32x4*)&mlps[mbase]);
        bf16x8 m1  = BC8(*(const u32x4*)&mlps[mbase + 32]);
        bf16x8 m0l = BC8(*(const u32x4*)&mlps[mbase + 64]);
        bf16x8 m1l = BC8(*(const u32x4*)&mlps[mbase + 96]);
        f32x4 hacc = {0.f, 0.f, 0.f, 0.f};
        hacc = MFMA16(m0,  fW10h, hacc);
        hacc = MFMA16(m1,  fW11h, hacc);
        hacc = MFMA16(m0l, fW10h, hacc);
        hacc = MFMA16(m1l, fW11h, hacc);
        hacc = MFMA16(m0,  fW10l, hacc);
        hacc = MFMA16(m1,  fW11l, hacc);
#pragma unroll
        for (int q = 0; q < 4; q++) {
            float hv = fmaxf(hacc[q] + b1j, 0.0f);
            unsigned short hh, ll;
            split2(hv, hh, ll);
            hids[(l4 * 4 + q) * MS + j1]      = hh;
            hids[(l4 * 4 + q) * MS + 64 + j1] = ll;
        }
        __syncthreads();   // hid ready
        bf16x8 h0  = BC8(*(const u32x4*)&hids[mbase]);
        bf16x8 h1  = BC8(*(const u32x4*)&hids[mbase + 32]);
        bf16x8 h0l = BC8(*(const u32x4*)&hids[mbase + 64]);
        bf16x8 h1l = BC8(*(const u32x4*)&hids[mbase + 96]);
        f32x4 oacc = {0.f, 0.f, 0.f, 0.f};
        oacc = MFMA16(h0,  fW20h, oacc);
        oacc = MFMA16(h1,  fW21h, oacc);
        oacc = MFMA16(h0l, fW20h, oacc);
        oacc = MFMA16(h1l, fW21h, oacc);
        oacc = MFMA16(h0,  fW20l, oacc);
        oacc = MFMA16(h1,  fW21l, oacc);
        lat0 += oacc[0] + b2j;
        lat1 += oacc[1] + b2j;
        lat2 += oacc[2] + b2j;
        lat3 += oacc[3] + b2j;
    };

    // ---- post-encoder MLP: latest += mlp(h_enc, cn_0, fc_0) ----
    stage_cnfc(0);
    __syncthreads();       // mlps complete (h written before last enc barrier)
    run_mlp();

    // ---- decoder: 48 steps ----
    for (int t = 0; t < 48; ++t) {
        // xn = norm(latest) -> xh.x (hi+lo)
        float n0 = (lat0 - hmj) * hsj;
        float n1 = (lat1 - hmj) * hsj;
        float n2 = (lat2 - hmj) * hsj;
        float n3 = (lat3 - hmj) * hsj;
        unsigned short hh, ll;
        split2(n0, hh, ll);
        xh[(l4 * 4 + 0) * XS + j1] = hh; xh[(l4 * 4 + 0) * XS + 96 + j1] = ll;
        split2(n1, hh, ll);
        xh[(l4 * 4 + 1) * XS + j1] = hh; xh[(l4 * 4 + 1) * XS + 96 + j1] = ll;
        split2(n2, hh, ll);
        xh[(l4 * 4 + 2) * XS + j1] = hh; xh[(l4 * 4 + 2) * XS + 96 + j1] = ll;
        split2(n3, hh, ll);
        xh[(l4 * 4 + 3) * XS + j1] = hh; xh[(l4 * 4 + 3) * XS + 96 + j1] = ll;
        __syncthreads();   // D1

        lstm_mfma_phase();
        __syncthreads();   // D2

        gate_phase();
        stage_cnfc(t);
        __syncthreads();   // D3

        run_mlp();         // internal barrier D4

        out[((size_t)(b0 + l4 * 4 + 0) * 48 + t) * 64 + j1] = lat0;
        out[((size_t)(b0 + l4 * 4 + 1) * 48 + t) * 64 + j1] = lat1;
        out[((size_t)(b0 + l4 * 4 + 2) * 48 + t) * 64 + j1] = lat2;
        out[((size_t)(b0 + l4 * 4 + 3) * 48 + t) * 64 + j1] = lat3;
    }
}

extern "C" void kernel_launch(void* const* d_in, const int* in_sizes, int n_in,
                              void* d_out, int out_size, void* d_ws, size_t ws_size,
                              hipStream_t stream) {
    tutina_kernel<<<dim3(256), dim3(256), 0, stream>>>(
        (const float*)d_in[0],  (const float*)d_in[1],  (const float*)d_in[2],
        (const float*)d_in[3],  (const float*)d_in[4],  (const float*)d_in[5],
        (const float*)d_in[6],  (const float*)d_in[7],  (const float*)d_in[8],
        (const float*)d_in[9],  (const float*)d_in[10], (const float*)d_in[11],
        (const float*)d_in[12], (const float*)d_in[13], (const float*)d_in[14],
        (const float*)d_in[15], (const float*)d_in[16], (const float*)d_in[17],
        (float*)d_out);
}